// Round 5
// baseline (1142.730 us; speedup 1.0000x reference)
//
#include <hip/hip_runtime.h>
#include <cstdint>
#include <cstddef>

#define KBOX 4096
#define NMS_THRESH 0.6f

// ---- workspace layout (bytes) ----
static constexpr size_t WS_SB   = 0;                              // float4[KBOX]   sorted boxes
static constexpr size_t WS_AREA = 65536;                          // float[KBOX]    sorted areas
static constexpr size_t WS_SS   = 81920;                          // float[KBOX]    sorted scores
static constexpr size_t WS_ORD  = 98304;                          // int[KBOX]      sorted orig idx
static constexpr size_t WS_MASK = 114688;                         // u64[KBOX*64]   iou mask (2 MB)

// Kernel A: gather scores, bitonic-sort 64-bit keys in LDS, emit sorted arrays.
// key = (score_bits << 32) | (0xFFFFFFFF - i)  -> descending sort == stable argsort(-scores)
__global__ __launch_bounds__(1024) void k_sort(const float* __restrict__ yolo,
                                               const int* __restrict__ bidx,
                                               float4* __restrict__ sb,
                                               float* __restrict__ area,
                                               float* __restrict__ ss,
                                               int* __restrict__ sord) {
    #pragma clang fp contract(off)
    __shared__ unsigned long long keys[KBOX];
    const int tid = threadIdx.x;

    for (int p = tid; p < KBOX; p += 1024) {
        size_t idx = (size_t)(unsigned)bidx[p];
        float s = yolo[idx * 5 + 4];
        keys[p] = ((unsigned long long)__float_as_uint(s) << 32)
                | (unsigned long long)(0xFFFFFFFFu - (unsigned)p);
    }

    for (int k = 2; k <= KBOX; k <<= 1) {
        for (int j = k >> 1; j > 0; j >>= 1) {
            __syncthreads();
            for (int i = tid; i < KBOX; i += 1024) {
                int ixj = i ^ j;
                if (ixj > i) {
                    unsigned long long a = keys[i], b = keys[ixj];
                    // descending overall
                    bool sw = ((i & k) == 0) ? (a < b) : (a > b);
                    if (sw) { keys[i] = b; keys[ixj] = a; }
                }
            }
        }
    }
    __syncthreads();

    for (int p = tid; p < KBOX; p += 1024) {
        unsigned long long key = keys[p];
        unsigned o = 0xFFFFFFFFu - (unsigned)(key & 0xFFFFFFFFull);
        float s = __uint_as_float((unsigned)(key >> 32));
        size_t idx = (size_t)(unsigned)bidx[o];
        float x1 = yolo[idx * 5 + 0];
        float y1 = yolo[idx * 5 + 1];
        float x2 = yolo[idx * 5 + 2];
        float y2 = yolo[idx * 5 + 3];
        sb[p] = make_float4(x1, y1, x2, y2);
        area[p] = (x2 - x1 + 1.0f) * (y2 - y1 + 1.0f);   // same op order as reference
        ss[p] = s;
        sord[p] = (int)o;
    }
}

// Kernel B: one wave per row i. Step k: lanes compute IoU(i, k*64+lane);
// __ballot gives mask word k of row i. Lane k keeps word k, coalesced store.
__global__ __launch_bounds__(256) void k_mask(const float4* __restrict__ sb,
                                              const float* __restrict__ area,
                                              unsigned long long* __restrict__ mask) {
    #pragma clang fp contract(off)
    int gid = blockIdx.x * 256 + threadIdx.x;
    int i = gid >> 6;          // wave-uniform (256 % 64 == 0)
    int lane = gid & 63;

    float4 bi = sb[i];
    float ai = area[i];
    unsigned long long myword = 0ull;

    for (int k = 0; k < 64; ++k) {
        int j = k * 64 + lane;
        float4 bj = sb[j];
        float xx1 = fmaxf(bi.x, bj.x);
        float yy1 = fmaxf(bi.y, bj.y);
        float xx2 = fminf(bi.z, bj.z);
        float yy2 = fminf(bi.w, bj.w);
        float w = fmaxf(0.0f, xx2 - xx1 + 1.0f);
        float h = fmaxf(0.0f, yy2 - yy1 + 1.0f);
        float inter = w * h;
        float uni = (ai + area[j]) - inter;   // areas_i + areas_j - inter
        float iou = inter / uni;
        bool pred = (iou >= NMS_THRESH) && (j > i);
        unsigned long long bal = __ballot(pred);
        if (k == lane) myword = bal;
    }
    mask[(size_t)i * 64 + lane] = myword;
}

// Kernel C (fused reduce + output): one block, 1024 threads.
// Phase 1 (wave 0 only): sequential greedy reduce. Lane t owns remv word t.
// Chunk c: rows i in [c*64,c*64+64) test bits of remv word c, which every
// lane shadows in `sup` (uniform load of mask[i*64+c]) -> serial chain is
// register-only; one shfl per chunk.
// Phase 2 (all 1024 threads): write bbox_pred / bbox_num / nms_keep_idx.
__global__ __launch_bounds__(1024) void k_reduce_out(const unsigned long long* __restrict__ mask,
                                                     const float4* __restrict__ sb,
                                                     const float* __restrict__ ss,
                                                     const int* __restrict__ sord,
                                                     float* __restrict__ out) {
    __shared__ unsigned long long keep_lds[64];
    const int tid = threadIdx.x;

    if (tid < 64) {
        int lane = tid;
        unsigned long long remv = 0ull;

        for (int c = 0; c < 64; ++c) {
            unsigned long long sup = __shfl(remv, c);   // remv word c so far
            #pragma unroll
            for (int u = 0; u < 64; ++u) {
                int i = c * 64 + u;
                // single-pass 2 MB stream: bypass L1, keep L2 path short
                unsigned long long m  = __builtin_nontemporal_load(&mask[(size_t)i * 64 + lane]);
                unsigned long long bc = __builtin_nontemporal_load(&mask[(size_t)i * 64 + c]);
                if (!((sup >> u) & 1ull)) {   // row i kept -> suppress its overlaps
                    remv |= m;
                    sup  |= bc;
                }
            }
        }

        unsigned long long kw = ~remv;
        keep_lds[lane] = kw;

        int cnt = __popcll(kw);
        for (int off = 32; off > 0; off >>= 1) cnt += __shfl_down(cnt, off);
        if (lane == 0) out[(size_t)KBOX * 6] = (float)cnt;   // bbox_num
    }
    __syncthreads();

    for (int p = tid; p < KBOX; p += 1024) {
        bool keep = (keep_lds[p >> 6] >> (p & 63)) & 1ull;
        float4 b = sb[p];
        float s = ss[p];
        int o = sord[p];

        float* row = out + (size_t)p * 6;
        row[0] = 0.0f;
        row[1] = keep ? s   : 0.0f;
        row[2] = keep ? b.x : 0.0f;
        row[3] = keep ? b.y : 0.0f;
        row[4] = keep ? b.z : 0.0f;
        row[5] = keep ? b.w : 0.0f;

        // nms_keep_idx (float-cast of int output; -1 when suppressed)
        out[(size_t)KBOX * 6 + 1 + p] = keep ? (float)o : -1.0f;
    }
}

extern "C" void kernel_launch(void* const* d_in, const int* in_sizes, int n_in,
                              void* d_out, int out_size, void* d_ws, size_t ws_size,
                              hipStream_t stream) {
    const float* yolo = (const float*)d_in[0];   // [4e6, 5] f32
    const int* bidx   = (const int*)d_in[1];     // [4096] i32
    float* out = (float*)d_out;                  // 4096*6 + 1 + 4096 floats

    char* ws = (char*)d_ws;                      // needs ~2.2 MB
    float4* sb  = (float4*)(ws + WS_SB);
    float* area = (float*)(ws + WS_AREA);
    float* ss   = (float*)(ws + WS_SS);
    int* sord   = (int*)(ws + WS_ORD);
    unsigned long long* mask = (unsigned long long*)(ws + WS_MASK);

    k_sort<<<1, 1024, 0, stream>>>(yolo, bidx, sb, area, ss, sord);
    k_mask<<<(KBOX * 64) / 256, 256, 0, stream>>>(sb, area, mask);
    k_reduce_out<<<1, 1024, 0, stream>>>(mask, sb, ss, sord, out);
}

// Round 6
// 344.162 us; speedup vs baseline: 3.3203x; 3.3203x over previous
//
#include <hip/hip_runtime.h>
#include <cstdint>
#include <cstddef>

#define KBOX 4096
#define NMS_THRESH 0.6f

typedef unsigned long long u64;

// ---- workspace layout (bytes) ----
static constexpr size_t WS_SB   = 0;        // float4[KBOX]   64 KB  sorted boxes
static constexpr size_t WS_AREA = 65536;    // float[KBOX]    16 KB  sorted areas
static constexpr size_t WS_SS   = 81920;    // float[KBOX]    16 KB  sorted scores
static constexpr size_t WS_ORD  = 98304;    // int[KBOX]      16 KB  sorted orig idx
static constexpr size_t WS_KEYS = 114688;   // u64[KBOX]      32 KB  sort keys
static constexpr size_t WS_MASK = 147456;   // u64[KBOX*64]    2 MB  iou mask

// Kernel 1: build sort keys. key = (score_bits<<32) | (0xFFFFFFFF - p).
// Scores are positive floats -> uint bit-pattern is order-preserving; low word
// makes keys UNIQUE and reproduces stable argsort(-scores) tie-breaking.
__global__ __launch_bounds__(256) void k_keys(const float* __restrict__ yolo,
                                              const int* __restrict__ bidx,
                                              u64* __restrict__ keys) {
    int p = blockIdx.x * 256 + threadIdx.x;
    size_t idx = (size_t)(unsigned)bidx[p];
    float s = yolo[idx * 5 + 4];
    keys[p] = ((u64)__float_as_uint(s) << 32)
            | (u64)(0xFFFFFFFFu - (unsigned)p);
}

// Kernel 2: rank-sort. Keys are unique, so rank[p] = #{q : key[q] > key[p]}
// is the exact stable descending permutation. One wave per p; lanes scan 64
// keys per step via ballot+popc (keys are L2/L1-resident, 32 KB).
// Lane 0 then gathers the box and writes sorted arrays at position rank.
__global__ __launch_bounds__(256) void k_rank(const u64* __restrict__ keys,
                                              const float* __restrict__ yolo,
                                              const int* __restrict__ bidx,
                                              float4* __restrict__ sb,
                                              float* __restrict__ area,
                                              float* __restrict__ ss,
                                              int* __restrict__ sord) {
    #pragma clang fp contract(off)
    int gid = blockIdx.x * 256 + threadIdx.x;
    int p = gid >> 6;          // wave-uniform
    int lane = gid & 63;

    u64 kp = keys[p];
    int cnt = 0;
    for (int k = 0; k < 64; ++k) {
        u64 kq = keys[k * 64 + lane];            // coalesced
        cnt += __popcll(__ballot(kq > kp));      // wave-uniform increment
    }

    if (lane == 0) {
        int r = cnt;                              // rank = sorted position
        size_t idx = (size_t)(unsigned)bidx[p];
        float x1 = yolo[idx * 5 + 0];
        float y1 = yolo[idx * 5 + 1];
        float x2 = yolo[idx * 5 + 2];
        float y2 = yolo[idx * 5 + 3];
        float s  = __uint_as_float((unsigned)(kp >> 32));
        sb[r] = make_float4(x1, y1, x2, y2);
        area[r] = (x2 - x1 + 1.0f) * (y2 - y1 + 1.0f);   // same op order as reference
        ss[r] = s;
        sord[r] = p;
    }
}

// Kernel 3: one wave per row i. Step k: lanes compute IoU(i, k*64+lane);
// __ballot gives mask word k of row i. Lane k keeps word k, coalesced store.
__global__ __launch_bounds__(256) void k_mask(const float4* __restrict__ sb,
                                              const float* __restrict__ area,
                                              u64* __restrict__ mask) {
    #pragma clang fp contract(off)
    int gid = blockIdx.x * 256 + threadIdx.x;
    int i = gid >> 6;          // wave-uniform
    int lane = gid & 63;

    float4 bi = sb[i];
    float ai = area[i];
    u64 myword = 0ull;

    for (int k = 0; k < 64; ++k) {
        int j = k * 64 + lane;
        float4 bj = sb[j];
        float xx1 = fmaxf(bi.x, bj.x);
        float yy1 = fmaxf(bi.y, bj.y);
        float xx2 = fminf(bi.z, bj.z);
        float yy2 = fminf(bi.w, bj.w);
        float w = fmaxf(0.0f, xx2 - xx1 + 1.0f);
        float h = fmaxf(0.0f, yy2 - yy1 + 1.0f);
        float inter = w * h;
        float uni = (ai + area[j]) - inter;   // areas_i + areas_j - inter
        float iou = inter / uni;
        bool pred = (iou >= NMS_THRESH) && (j > i);
        u64 bal = __ballot(pred);
        if (k == lane) myword = bal;
    }
    mask[(size_t)i * 64 + lane] = myword;
}

// Kernel 4 (fused reduce + output), one block of 1024 threads.
// LDS double-buffer: waves 1..15 prefetch mask chunk c+1 (64 rows x 512 B =
// 32 KB) into stage[(c+1)&1] while wave 0 runs the serial greedy chain on
// chunk c from stage[c&1]. The chain per row is: m = LDS row word (per-lane),
// bc = LDS broadcast word (uniform), wave-uniform bit-test, two ORs. All LDS
// reads are off the serial dependency chain -> compiler pipelines them with
// fine-grained lgkmcnt instead of the previous one-wave exposed global
// latency (952 us -> VGPR=16, fully serialized loads).
__global__ __launch_bounds__(1024) void k_reduce_out(const u64* __restrict__ mask,
                                                     const float4* __restrict__ sb,
                                                     const float* __restrict__ ss,
                                                     const int* __restrict__ sord,
                                                     float* __restrict__ out) {
    __shared__ u64 stage[2][64 * 64];   // 2 x 32 KB
    __shared__ u64 keep_lds[64];
    const int tid = threadIdx.x;

    // preload chunk 0
    for (int t = tid; t < 4096; t += 1024) stage[0][t] = mask[t];
    __syncthreads();

    u64 remv = 0ull;

    for (int c = 0; c < 64; ++c) {
        // helper waves prefetch chunk c+1
        if (tid >= 64 && c + 1 < 64) {
            const u64* src = mask + (size_t)(c + 1) * 4096;
            u64* dst = stage[(c + 1) & 1];
            for (int t = tid - 64; t < 4096; t += 960) dst[t] = src[t];
        }
        // wave 0: serial greedy chain on chunk c
        if (tid < 64) {
            const int lane = tid;
            const u64* buf = stage[c & 1];
            u64 sup = __shfl(remv, c);   // remv word c so far (uniform)
            #pragma unroll
            for (int u = 0; u < 64; ++u) {
                u64 m  = buf[u * 64 + lane];   // per-lane word of row i
                u64 bc = buf[u * 64 + c];      // broadcast: row i word c
                if (!((sup >> u) & 1ull)) {    // row kept -> suppress overlaps
                    remv |= m;
                    sup  |= bc;
                }
            }
        }
        __syncthreads();
    }

    if (tid < 64) {
        u64 kw = ~remv;
        keep_lds[tid] = kw;
        int cnt = __popcll(kw);
        for (int off = 32; off > 0; off >>= 1) cnt += __shfl_down(cnt, off);
        if (tid == 0) out[(size_t)KBOX * 6] = (float)cnt;   // bbox_num
    }
    __syncthreads();

    // output fan-out: bbox_pred rows + nms_keep_idx (all elements every call)
    for (int p = tid; p < KBOX; p += 1024) {
        bool keep = (keep_lds[p >> 6] >> (p & 63)) & 1ull;
        float4 b = sb[p];
        float s = ss[p];
        int o = sord[p];

        float* row = out + (size_t)p * 6;
        row[0] = 0.0f;
        row[1] = keep ? s   : 0.0f;
        row[2] = keep ? b.x : 0.0f;
        row[3] = keep ? b.y : 0.0f;
        row[4] = keep ? b.z : 0.0f;
        row[5] = keep ? b.w : 0.0f;

        out[(size_t)KBOX * 6 + 1 + p] = keep ? (float)o : -1.0f;
    }
}

extern "C" void kernel_launch(void* const* d_in, const int* in_sizes, int n_in,
                              void* d_out, int out_size, void* d_ws, size_t ws_size,
                              hipStream_t stream) {
    const float* yolo = (const float*)d_in[0];   // [4e6, 5] f32
    const int* bidx   = (const int*)d_in[1];     // [4096] i32
    float* out = (float*)d_out;                  // 4096*6 + 1 + 4096 floats

    char* ws = (char*)d_ws;                      // ~2.15 MB used
    float4* sb  = (float4*)(ws + WS_SB);
    float* area = (float*)(ws + WS_AREA);
    float* ss   = (float*)(ws + WS_SS);
    int* sord   = (int*)(ws + WS_ORD);
    u64* keys   = (u64*)(ws + WS_KEYS);
    u64* mask   = (u64*)(ws + WS_MASK);

    k_keys<<<KBOX / 256, 256, 0, stream>>>(yolo, bidx, keys);
    k_rank<<<(KBOX * 64) / 256, 256, 0, stream>>>(keys, yolo, bidx, sb, area, ss, sord);
    k_mask<<<(KBOX * 64) / 256, 256, 0, stream>>>(sb, area, mask);
    k_reduce_out<<<1, 1024, 0, stream>>>(mask, sb, ss, sord, out);
}

// Round 12
// 336.311 us; speedup vs baseline: 3.3978x; 1.0233x over previous
//
#include <hip/hip_runtime.h>
#include <cstdint>
#include <cstddef>

#define KBOX 4096
#define NMS_THRESH 0.6f

typedef unsigned long long u64;

// ---- workspace layout (bytes) ----
static constexpr size_t WS_SB   = 0;        // float4[KBOX]   64 KB  sorted boxes
static constexpr size_t WS_AREA = 65536;    // float[KBOX]    16 KB  sorted areas
static constexpr size_t WS_SS   = 81920;    // float[KBOX]    16 KB  sorted scores
static constexpr size_t WS_ORD  = 98304;    // int[KBOX]      16 KB  sorted orig idx
static constexpr size_t WS_KEYS = 114688;   // u64[KBOX]      32 KB  sort keys
static constexpr size_t WS_MASK = 147456;   // u64[KBOX*64]    2 MB  iou mask

// Kernel 1: build sort keys. key = (score_bits<<32) | (0xFFFFFFFF - p).
// Scores are positive floats -> uint bit-pattern is order-preserving; low word
// makes keys UNIQUE and reproduces stable argsort(-scores) tie-breaking.
__global__ __launch_bounds__(256) void k_keys(const float* __restrict__ yolo,
                                              const int* __restrict__ bidx,
                                              u64* __restrict__ keys) {
    int p = blockIdx.x * 256 + threadIdx.x;
    size_t idx = (size_t)(unsigned)bidx[p];
    float s = yolo[idx * 5 + 4];
    keys[p] = ((u64)__float_as_uint(s) << 32)
            | (u64)(0xFFFFFFFFu - (unsigned)p);
}

// Kernel 2: rank-sort. Keys are unique, so rank[p] = #{q : key[q] > key[p]}
// is the exact stable descending permutation. One wave per p; lanes scan 64
// keys per step via ballot+popc (keys are L2/L1-resident, 32 KB).
// Lane 0 then gathers the box and writes sorted arrays at position rank.
__global__ __launch_bounds__(256) void k_rank(const u64* __restrict__ keys,
                                              const float* __restrict__ yolo,
                                              const int* __restrict__ bidx,
                                              float4* __restrict__ sb,
                                              float* __restrict__ area,
                                              float* __restrict__ ss,
                                              int* __restrict__ sord) {
    #pragma clang fp contract(off)
    int gid = blockIdx.x * 256 + threadIdx.x;
    int p = gid >> 6;          // wave-uniform
    int lane = gid & 63;

    u64 kp = keys[p];
    int cnt = 0;
    for (int k = 0; k < 64; ++k) {
        u64 kq = keys[k * 64 + lane];            // coalesced
        cnt += __popcll(__ballot(kq > kp));      // wave-uniform increment
    }

    if (lane == 0) {
        int r = cnt;                              // rank = sorted position
        size_t idx = (size_t)(unsigned)bidx[p];
        float x1 = yolo[idx * 5 + 0];
        float y1 = yolo[idx * 5 + 1];
        float x2 = yolo[idx * 5 + 2];
        float y2 = yolo[idx * 5 + 3];
        float s  = __uint_as_float((unsigned)(kp >> 32));
        sb[r] = make_float4(x1, y1, x2, y2);
        area[r] = (x2 - x1 + 1.0f) * (y2 - y1 + 1.0f);   // same op order as reference
        ss[r] = s;
        sord[r] = p;
    }
}

// Kernel 3: one wave per row i. Step k: lanes compute IoU(i, k*64+lane);
// __ballot gives mask word k of row i. Lane k keeps word k, coalesced store.
__global__ __launch_bounds__(256) void k_mask(const float4* __restrict__ sb,
                                              const float* __restrict__ area,
                                              u64* __restrict__ mask) {
    #pragma clang fp contract(off)
    int gid = blockIdx.x * 256 + threadIdx.x;
    int i = gid >> 6;          // wave-uniform
    int lane = gid & 63;

    float4 bi = sb[i];
    float ai = area[i];
    u64 myword = 0ull;

    for (int k = 0; k < 64; ++k) {
        int j = k * 64 + lane;
        float4 bj = sb[j];
        float xx1 = fmaxf(bi.x, bj.x);
        float yy1 = fmaxf(bi.y, bj.y);
        float xx2 = fminf(bi.z, bj.z);
        float yy2 = fminf(bi.w, bj.w);
        float w = fmaxf(0.0f, xx2 - xx1 + 1.0f);
        float h = fmaxf(0.0f, yy2 - yy1 + 1.0f);
        float inter = w * h;
        float uni = (ai + area[j]) - inter;   // areas_i + areas_j - inter
        float iou = inter / uni;
        bool pred = (iou >= NMS_THRESH) && (j > i);
        u64 bal = __ballot(pred);
        if (k == lane) myword = bal;
    }
    mask[(size_t)i * 64 + lane] = myword;
}

// Kernel 4 (fused reduce + output), one block of 1024 threads.
// Waves 1..15 double-buffer-prefetch the next 64-row mask chunk (32 KB) into
// LDS while wave 0 processes the current chunk in two phases:
//   Phase A (serial, register-only): the greedy keep/suppress chain only
//     needs word c of each in-chunk row. Those 64 words are preloaded
//     one-per-lane (bcu); the 64-step chain uses __shfl(bcu,u) broadcasts
//     (independent of chain state). Critical path per step is
//     shift/and -> cndmask -> or (~3-4 dependent VALU ops); the `kept`
//     accumulation is a parallel side-chain.
//   Phase B (parallel): with the uniform `kept` bitmask known, each lane ORs
//     the mask words of kept rows into its remv word -- 64 INDEPENDENT LDS
//     loads, branchless masked OR, fully pipelinable (2-way bank alias only,
//     which is free on gfx950).
// This removes the load->use serialization that held the previous version at
// 220 us (VGPR=16: compiler would not hoist loads past the conditional chain).
__global__ __launch_bounds__(1024) void k_reduce_out(const u64* __restrict__ mask,
                                                     const float4* __restrict__ sb,
                                                     const float* __restrict__ ss,
                                                     const int* __restrict__ sord,
                                                     float* __restrict__ out) {
    __shared__ u64 stage[2][64 * 64];   // 2 x 32 KB
    __shared__ u64 keep_lds[64];
    const int tid = threadIdx.x;

    // preload chunk 0
    for (int t = tid; t < 4096; t += 1024) stage[0][t] = mask[t];
    __syncthreads();

    u64 remv = 0ull;

    for (int c = 0; c < 64; ++c) {
        // helper waves prefetch chunk c+1
        if (tid >= 64 && c + 1 < 64) {
            const u64* src = mask + (size_t)(c + 1) * 4096;
            u64* dst = stage[(c + 1) & 1];
            for (int t = tid - 64; t < 4096; t += 960) dst[t] = src[t];
        }
        if (tid < 64) {
            const int lane = tid;
            const u64* buf = stage[c & 1];

            // ---- Phase A: serial chain on diagonal words (registers only)
            u64 bcu = buf[(lane << 6) + c];     // row `lane`'s word c
            u64 sup = __shfl(remv, c);          // remv word c (uniform)
            u64 kept = 0ull;
            #pragma unroll
            for (int u = 0; u < 64; ++u) {
                u64 bc_u = __shfl(bcu, u);                  // row u's word c (off-chain)
                u64 sbit = (sup >> u) & 1ull;               // 1 if row u suppressed
                kept |= (sbit ^ 1ull) << u;                 // side-chain
                sup  |= sbit ? 0ull : bc_u;                 // cndmask + or (critical)
            }

            // ---- Phase B: parallel masked OR of kept rows' mask words
            u64 acc = 0ull;
            #pragma unroll
            for (int u = 0; u < 64; ++u) {
                u64 m = buf[(u << 6) | lane];               // independent loads
                acc |= m & (0ull - ((kept >> u) & 1ull));
            }
            remv |= acc;
        }
        __syncthreads();
    }

    if (tid < 64) {
        u64 kw = ~remv;
        keep_lds[tid] = kw;
        int cnt = __popcll(kw);
        for (int off = 32; off > 0; off >>= 1) cnt += __shfl_down(cnt, off);
        if (tid == 0) out[(size_t)KBOX * 6] = (float)cnt;   // bbox_num
    }
    __syncthreads();

    // output fan-out: bbox_pred rows + nms_keep_idx (all elements every call)
    for (int p = tid; p < KBOX; p += 1024) {
        bool keep = (keep_lds[p >> 6] >> (p & 63)) & 1ull;
        float4 b = sb[p];
        float s = ss[p];
        int o = sord[p];

        float* row = out + (size_t)p * 6;
        row[0] = 0.0f;
        row[1] = keep ? s   : 0.0f;
        row[2] = keep ? b.x : 0.0f;
        row[3] = keep ? b.y : 0.0f;
        row[4] = keep ? b.z : 0.0f;
        row[5] = keep ? b.w : 0.0f;

        out[(size_t)KBOX * 6 + 1 + p] = keep ? (float)o : -1.0f;
    }
}

extern "C" void kernel_launch(void* const* d_in, const int* in_sizes, int n_in,
                              void* d_out, int out_size, void* d_ws, size_t ws_size,
                              hipStream_t stream) {
    const float* yolo = (const float*)d_in[0];   // [4e6, 5] f32
    const int* bidx   = (const int*)d_in[1];     // [4096] i32
    float* out = (float*)d_out;                  // 4096*6 + 1 + 4096 floats

    char* ws = (char*)d_ws;                      // ~2.15 MB used
    float4* sb  = (float4*)(ws + WS_SB);
    float* area = (float*)(ws + WS_AREA);
    float* ss   = (float*)(ws + WS_SS);
    int* sord   = (int*)(ws + WS_ORD);
    u64* keys   = (u64*)(ws + WS_KEYS);
    u64* mask   = (u64*)(ws + WS_MASK);

    k_keys<<<KBOX / 256, 256, 0, stream>>>(yolo, bidx, keys);
    k_rank<<<(KBOX * 64) / 256, 256, 0, stream>>>(keys, yolo, bidx, sb, area, ss, sord);
    k_mask<<<(KBOX * 64) / 256, 256, 0, stream>>>(sb, area, mask);
    k_reduce_out<<<1, 1024, 0, stream>>>(mask, sb, ss, sord, out);
}